// Round 25
// baseline (43.929 us; speedup 1.0000x reference)
//
#include <hip/hip_runtime.h>

typedef short short8 __attribute__((ext_vector_type(8)));
typedef float f32x4 __attribute__((ext_vector_type(4)));
typedef float f32x2 __attribute__((ext_vector_type(2)));

#define NN 8
#define CI 64
#define CO 128
#define HH 128
#define WW 128
#define PH 132             // padded (2-halo each side)
#define PW 132
#define MU 0.033333333333333333f

#define WS_W_BYTES (9 * 128 * 64 * 2)        // 147456
#define WS_T_OFF   WS_W_BYTES
#define WS_T_BYTES (NN * PH * PW * 4)        // 557568
#define WS_X_OFF   (WS_T_OFF + WS_T_BYTES)   // 705024
#define WS_X_BYTES ((size_t)NN * PH * PW * CI * 2)   // 17842176
#define WS_NB_OFF  (WS_X_OFF + WS_X_BYTES)   // 18547200
#define WS_TOTAL   (WS_NB_OFF + WS_T_BYTES)  // ~19.1 MB

__device__ __forceinline__ unsigned short f2bf(float f) {
  unsigned u = __float_as_uint(f);
  u += 0x7fffu + ((u >> 16) & 1u);     // round-to-nearest-even
  return (unsigned short)(u >> 16);
}

__device__ __forceinline__ void g2lds16(const void* g, void* l) {
  __builtin_amdgcn_global_load_lds(
      (const __attribute__((address_space(1))) unsigned int*)g,
      (__attribute__((address_space(3))) unsigned int*)l, 16, 0, 0);
}
__device__ __forceinline__ void g2lds4(const void* g, void* l) {
  __builtin_amdgcn_global_load_lds(
      (const __attribute__((address_space(1))) unsigned int*)g,
      (__attribute__((address_space(3))) unsigned int*)l, 4, 0, 0);
}

// ================= FAST PATH =================
// prep v2 (R24-proven): float2 pixel loads, 4x128 tiles, NHWC bf16 repack.
__global__ __launch_bounds__(256) void prep_kernel(
    const float* __restrict__ in, const float* __restrict__ w,
    unsigned short* __restrict__ ws_w, float* __restrict__ ws_T,
    short8* __restrict__ ws_x) {
  const int b = blockIdx.x, tid = threadIdx.x;
  if (b < 256) {                             // 256 blocks x 512 px
    __shared__ short8 lx[512][8];            // [px][slot^(px&7)], 64KB
    const int n = b >> 5, quad = b & 31;     // 32 row-quads
    const int rl = tid >> 6;                 // row 0..3
    const int x2 = (tid & 63) * 2;           // even x
    const int r = quad * 4 + rl;
    const float* src = in + ((size_t)(n * CI) * HH + r) * WW + x2;
    const int px0 = rl * 128 + x2;
    float ts0 = 0.f, ts1 = 0.f;
    #pragma unroll
    for (int g = 0; g < 8; ++g) {
      short8 pk0, pk1;
      #pragma unroll
      for (int j = 0; j < 8; ++j) {
        const f32x2 v = *(const f32x2*)(src + (size_t)(g * 8 + j) * (HH * WW));
        ts0 += v[0]; ts1 += v[1];
        pk0[j] = (short)f2bf(v[0]);
        pk1[j] = (short)f2bf(v[1]);
      }
      lx[px0][g ^ (px0 & 7)] = pk0;
      lx[px0 + 1][g ^ ((px0 + 1) & 7)] = pk1;
    }
    *(f32x2*)&ws_T[(n * PH + r + 2) * PW + (x2 + 2)] = (f32x2){ts0, ts1};
    __syncthreads();
    #pragma unroll
    for (int it = 0; it < 16; ++it) {        // coalesced NHWC store, 16B/lane
      const int G = it * 256 + tid;
      const int px2 = G >> 3, g2 = G & 7;
      const int r2 = quad * 4 + (px2 >> 7), x2b = px2 & 127;
      ws_x[((size_t)(n * PH + r2 + 2) * PW + (x2b + 2)) * 8 + g2] =
          lx[px2][g2 ^ (px2 & 7)];
    }
  } else if (b < 264) {                      // zero the padded borders
    const int n = b - 256;
    const short8 z = {0, 0, 0, 0, 0, 0, 0, 0};
    for (int e = tid; e < 1040 * 8; e += 256) {
      const int px = e >> 3, g = e & 7;
      int y, x;
      if (px < 528) { const int r4 = px / 132; y = (r4 < 2) ? r4 : r4 + 128; x = px - r4 * 132; }
      else { const int q = px - 528; const int c4 = q >> 7; x = (c4 < 2) ? c4 : c4 + 128; y = 2 + (q & 127); }
      ws_x[((size_t)(n * PH + y) * PW + x) * 8 + g] = z;
    }
    for (int e = tid; e < 1040; e += 256) {
      int y, x;
      if (e < 528) { const int r4 = e / 132; y = (r4 < 2) ? r4 : r4 + 128; x = e - r4 * 132; }
      else { const int q = e - 528; const int c4 = q >> 7; x = (c4 < 2) ? c4 : c4 + 128; y = 2 + (q & 127); }
      ws_T[(n * PH + y) * PW + x] = 0.f;
    }
  } else {                                   // weights, coalesced MFMA layout
    const int el = (b - 264) * 256 + tid;    // 0..9215 short8 elements
    const int lane = el & 63;
    const int idx = el >> 6;                 // 0..143 = tap*16 + cb*2 + ks
    const int ks = idx & 1, cb = (idx >> 1) & 7, tap = idx >> 4;
    const int lo = lane & 15, hi = lane >> 4;
    const int ky = (tap / 3) * 2, kx = (tap % 3) * 2;
    const float* wp = w + (size_t)((cb * 16 + lo) * 64 + ks * 32 + hi * 8) * 25
                        + ky * 5 + kx;
    short8 pk;
    #pragma unroll
    for (int j = 0; j < 8; ++j) pk[j] = (short)f2bf(wp[j * 25]);
    ((short8*)ws_w)[el] = pk;
  }
}

// nb: per-pixel neighbor plane, COMPACT [n][128][128] (16B-aligned reads)
__global__ __launch_bounds__(256) void nb_kernel(
    const float* __restrict__ ws_T, float* __restrict__ ws_nb) {
  const int p = blockIdx.x * 256 + threadIdx.x;   // 131072 interior pixels
  const int n = p >> 14, yx = p & 16383;
  const int y = yx >> 7, x = yx & 127;
  const float* Tb = ws_T + (size_t)(n * PH + y) * PW + x;
  float s = 0.f;
  #pragma unroll
  for (int ky = 0; ky < 5; ++ky)
    #pragma unroll
    for (int kx = 0; kx < 5; ++kx)
      if ((ky & 1) | (kx & 1)) s += Tb[ky * PW + kx];
  ws_nb[(size_t)p] = s * MU;
}

// conv v15: v14 regridded to 12-row halo staged ONCE per x-subtile, both
// y-substrips computed from it: j 8->4, barriers 16->8, halo DMA -25%.
// Wave owns 2 output rows (2w, 2w+1); acc 8x f32x4; 2-deep af pipeline
// (8 MFMAs/set cover the next set's 4 reads). W[36] in regs; VGPR ~225
// under the waves_per_eu(2,2)-pinned 256. XCD-pinned n=bid&7.
__global__ __launch_bounds__(256)
__attribute__((amdgpu_waves_per_eu(2, 2)))
void conv_kernel(
    const unsigned short* __restrict__ ws_w, const float* __restrict__ ws_nb,
    const unsigned short* __restrict__ ws_x, float* __restrict__ out) {
  __shared__ short8 halo[432 * 8];     // 55296 B: 12 rows x 36 cols, swizzled
  __shared__ float  nbt[256];          // 1 KB: 8 rows x 32 cols

  const int tid = threadIdx.x;
  const int wave = tid >> 6, lane = tid & 63;
  const int bid = blockIdx.x;          // 512 = (yslab*4 + quarter)*8 + n
  const int n = bid & 7;
  const int rest = bid >> 3;
  const int cob = rest & 3;            // co-quarter
  const int Y0 = (rest >> 2) * 8;      // 16 y-slabs of 8 rows
  const int lo = lane & 15, hi = lane >> 4;

  // quarter weights -> registers once (36 coalesced b128, L2-hot; static idx)
  const short8* wsv = (const short8*)ws_w;
  short8 W[36];                        // [tap*4 + cbl*2 + ks]
  #pragma unroll
  for (int k = 0; k < 36; ++k)
    W[k] = wsv[((k >> 2) * 16 + cob * 4 + (k & 3)) * 64 + lane];

  for (int j = 0; j < 4; ++j) {
    const int tx0 = j * 32;                  // 4 x-subtiles of the 8-row slab

    // halo DMA: 54 x 1KB chunks (12 rows x 36 cols), source pre-swizzled
    for (int k = wave; k < 54; k += 4) {
      const int pos = k * 8 + (lane >> 3);
      const int r = pos / 36, c = pos - r * 36;
      const int chunk = (lane & 7) ^ (pos & 7);
      const unsigned short* g =
          ws_x + ((size_t)(n * PH + Y0 + r) * PW + (tx0 + c)) * 64 + chunk * 8;
      g2lds16(g, (char*)halo + k * 1024);
    }
    {                                        // nb tile: wave w rows 2w,2w+1
      const float* g = ws_nb
          + (size_t)((n * 128 + Y0 + 2 * wave + (lane >> 5)) * 128)
          + tx0 + (lane & 31);
      g2lds4(g, (char*)nbt + wave * 256);
    }
    __syncthreads();                         // drains vmcnt (DMA complete)

    // acc init from NB; wave owns rows 2w, 2w+1 (r index)
    f32x4 a000, a001, a010, a011;            // [cbl0][r][h]
    f32x4 a100, a101, a110, a111;            // [cbl1][r][h]
    {
      const f32x4 n00 = *(const f32x4*)&nbt[(wave * 2 + 0) * 32 + 0  + hi * 4];
      const f32x4 n01 = *(const f32x4*)&nbt[(wave * 2 + 0) * 32 + 16 + hi * 4];
      const f32x4 n10 = *(const f32x4*)&nbt[(wave * 2 + 1) * 32 + 0  + hi * 4];
      const f32x4 n11 = *(const f32x4*)&nbt[(wave * 2 + 1) * 32 + 16 + hi * 4];
      a000 = n00; a001 = n01; a010 = n10; a011 = n11;
      a100 = n00; a101 = n01; a110 = n10; a111 = n11;
    }

    short8 Aaf00, Aaf01, Aaf10, Aaf11;       // [r][h]
    short8 Baf00, Baf01, Baf10, Baf11;

#define LOADSET(P, K) { \
      constexpr int tap_ = (K) >> 1, ks_ = (K) & 1; \
      constexpr int ty_ = (tap_ / 3) * 2, tx_ = (tap_ % 3) * 2; \
      const int q0_ = (wave * 2 + 0 + ty_) * 36 + (lo + tx_); \
      const int q1_ = q0_ + 36; \
      P##af00 = halo[q0_ * 8 + ((ks_ * 4 + hi) ^ (q0_ & 7))]; \
      P##af01 = halo[(q0_ + 16) * 8 + ((ks_ * 4 + hi) ^ ((q0_ + 16) & 7))]; \
      P##af10 = halo[q1_ * 8 + ((ks_ * 4 + hi) ^ (q1_ & 7))]; \
      P##af11 = halo[(q1_ + 16) * 8 + ((ks_ * 4 + hi) ^ ((q1_ + 16) & 7))]; \
    }
#define MFMASET(P, K) { \
      constexpr int tap_ = (K) >> 1, ks_ = (K) & 1; \
      const short8 w0_ = W[tap_ * 4 + 0 + ks_]; \
      const short8 w1_ = W[tap_ * 4 + 2 + ks_]; \
      a000 = __builtin_amdgcn_mfma_f32_16x16x32_bf16(P##af00, w0_, a000, 0, 0, 0); \
      a001 = __builtin_amdgcn_mfma_f32_16x16x32_bf16(P##af01, w0_, a001, 0, 0, 0); \
      a010 = __builtin_amdgcn_mfma_f32_16x16x32_bf16(P##af10, w0_, a010, 0, 0, 0); \
      a011 = __builtin_amdgcn_mfma_f32_16x16x32_bf16(P##af11, w0_, a011, 0, 0, 0); \
      a100 = __builtin_amdgcn_mfma_f32_16x16x32_bf16(P##af00, w1_, a100, 0, 0, 0); \
      a101 = __builtin_amdgcn_mfma_f32_16x16x32_bf16(P##af01, w1_, a101, 0, 0, 0); \
      a110 = __builtin_amdgcn_mfma_f32_16x16x32_bf16(P##af10, w1_, a110, 0, 0, 0); \
      a111 = __builtin_amdgcn_mfma_f32_16x16x32_bf16(P##af11, w1_, a111, 0, 0, 0); \
    }

    LOADSET(A, 0);  LOADSET(B, 1);
    MFMASET(A, 0);  LOADSET(A, 2);
    MFMASET(B, 1);  LOADSET(B, 3);
    MFMASET(A, 2);  LOADSET(A, 4);
    MFMASET(B, 3);  LOADSET(B, 5);
    MFMASET(A, 4);  LOADSET(A, 6);
    MFMASET(B, 5);  LOADSET(B, 7);
    MFMASET(A, 6);  LOADSET(A, 8);
    MFMASET(B, 7);  LOADSET(B, 9);
    MFMASET(A, 8);  LOADSET(A, 10);
    MFMASET(B, 9);  LOADSET(B, 11);
    MFMASET(A, 10); LOADSET(A, 12);
    MFMASET(B, 11); LOADSET(B, 13);
    MFMASET(A, 12); LOADSET(A, 14);
    MFMASET(B, 13); LOADSET(B, 15);
    MFMASET(A, 14); LOADSET(A, 16);
    MFMASET(B, 15); LOADSET(B, 17);
    MFMASET(A, 16);
    MFMASET(B, 17);
#undef LOADSET
#undef MFMASET

    // stores: h0+h1 cover full 128B lines; 8 dwordx4 per thread
    {
      const int gy0 = Y0 + wave * 2;
      const int gx0 = tx0 + hi * 4;
      const int co0 = cob * 32 + lo;
      float* o00 = &out[(((size_t)n * CO + co0) * HH + gy0) * WW + gx0];
      float* o01 = &out[(((size_t)n * CO + co0) * HH + gy0 + 1) * WW + gx0];
      float* o10 = &out[(((size_t)n * CO + co0 + 16) * HH + gy0) * WW + gx0];
      float* o11 = &out[(((size_t)n * CO + co0 + 16) * HH + gy0 + 1) * WW + gx0];
      *(f32x4*)(o00) = a000;      *(f32x4*)(o00 + 16) = a001;
      *(f32x4*)(o01) = a010;      *(f32x4*)(o01 + 16) = a011;
      *(f32x4*)(o10) = a100;      *(f32x4*)(o10 + 16) = a101;
      *(f32x4*)(o11) = a110;      *(f32x4*)(o11 + 16) = a111;
    }
    __syncthreads();                         // protect halo/nbt overwrite
  }
}

// ================= SAFE PATH (Round-2 proven, 705 KB ws) =================
__global__ __launch_bounds__(256) void prep_kernel_safe(
    const float* __restrict__ in, const float* __restrict__ w,
    unsigned short* __restrict__ ws_w, float* __restrict__ ws_T) {
  const int bid = blockIdx.x, tid = threadIdx.x;
  if (bid < 288) {
    const int el = bid * 256 + tid;
    const int tap = el >> 13;
    const int rem = el & 8191;
    const int co = rem >> 6, ic = rem & 63;
    const int ky = (tap / 3) * 2, kx = (tap % 3) * 2;
    ws_w[el] = f2bf(w[(co * 64 + ic) * 25 + ky * 5 + kx]);
  } else {
    const int p = (bid - 288) * 256 + tid;
    const int n = p >> 14;
    const int yx = p & 16383;
    const float* base = in + (size_t)n * CI * (HH * WW) + yx;
    float s = 0.f;
    #pragma unroll
    for (int ic = 0; ic < CI; ++ic) s += base[ic * (HH * WW)];
    ws_T[p] = s;
  }
}

#define SHR 12
#define SHC 36
#define SNPOS (SHR * SHC)

__global__ __launch_bounds__(256, 2) void conv_kernel_safe(
    const float* __restrict__ in, const unsigned short* __restrict__ ws_w,
    const float* __restrict__ ws_T, float* __restrict__ out) {
  __shared__ short8 in_lds[SNPOS * 8];
  __shared__ float T_lds[SNPOS];

  const int tid = threadIdx.x;
  const int t = blockIdx.x;
  const int n = blockIdx.y;
  const int ty0 = (t >> 2) * 8;
  const int tx0 = (t & 3) * 32;

  for (int e = tid; e < SNPOS * 8; e += 256) {
    const int slot = e / SNPOS;
    const int pos = e - slot * SNPOS;
    const int r = pos / SHC, c = pos - r * SHC;
    const int gy = ty0 + r - 2, gx = tx0 + c - 2;
    const bool ok = (gy >= 0 && gy < HH && gx >= 0 && gx < WW);
    const long off = ((long)(n * CI + slot * 8) * HH + gy) * WW + gx;
    short8 pk;
    #pragma unroll
    for (int j = 0; j < 8; ++j) {
      const float v = ok ? in[off + (long)j * (HH * WW)] : 0.f;
      pk[j] = (short)f2bf(v);
    }
    in_lds[pos * 8 + (slot ^ (pos & 7))] = pk;
  }
  for (int e = tid; e < SNPOS; e += 256) {
    const int r = e / SHC, c = e - r * SHC;
    const int gy = ty0 + r - 2, gx = tx0 + c - 2;
    T_lds[e] = (gy >= 0 && gy < HH && gx >= 0 && gx < WW)
                   ? ws_T[((size_t)n * HH + gy) * WW + gx] : 0.f;
  }
  __syncthreads();

  const int wave = tid >> 6;
  const int lane = tid & 63;
  const int lo = lane & 15;
  const int hi = lane >> 4;

  int py[4], pxc[4];
  #pragma unroll
  for (int f = 0; f < 4; ++f) {
    const int pb = wave * 64 + f * 16;
    py[f] = pb >> 5;
    pxc[f] = (pb & 31) + lo;
  }

  f32x4 acc[8][4];
  #pragma unroll
  for (int cb = 0; cb < 8; ++cb)
    #pragma unroll
    for (int f = 0; f < 4; ++f) acc[cb][f] = (f32x4){0.f, 0.f, 0.f, 0.f};

  const short8* wsv = (const short8*)ws_w;

  #pragma unroll
  for (int tap = 0; tap < 9; ++tap) {
    const int ty = (tap / 3) * 2, tx = (tap % 3) * 2;
    #pragma unroll
    for (int ks = 0; ks < 2; ++ks) {
      short8 bfrag[4];
      #pragma unroll
      for (int f = 0; f < 4; ++f) {
        const int pos = (py[f] + ty) * SHC + (pxc[f] + tx);
        bfrag[f] = in_lds[pos * 8 + ((ks * 4 + hi) ^ (pos & 7))];
      }
      #pragma unroll
      for (int cb = 0; cb < 8; ++cb) {
        const short8 afrag = wsv[(tap * 128 + cb * 16 + lo) * 8 + ks * 4 + hi];
        #pragma unroll
        for (int f = 0; f < 4; ++f)
          acc[cb][f] = __builtin_amdgcn_mfma_f32_16x16x32_bf16(
              afrag, bfrag[f], acc[cb][f], 0, 0, 0);
      }
    }
  }

  float nb[4];
  #pragma unroll
  for (int f = 0; f < 4; ++f) {
    float s = 0.f;
    #pragma unroll
    for (int ky = 0; ky < 5; ++ky)
      #pragma unroll
      for (int kx = 0; kx < 5; ++kx)
        if ((ky & 1) | (kx & 1))
          s += T_lds[(py[f] + ky) * SHC + (pxc[f] + kx)];
    nb[f] = s * MU;
  }

  #pragma unroll
  for (int cb = 0; cb < 8; ++cb) {
    #pragma unroll
    for (int f = 0; f < 4; ++f) {
      const int gy = ty0 + py[f];
      const int gx = tx0 + pxc[f];
      #pragma unroll
      for (int q = 0; q < 4; ++q) {
        const int co = cb * 16 + hi * 4 + q;
        out[(((size_t)n * CO + co) * HH + gy) * WW + gx] = acc[cb][f][q] + nb[f];
      }
    }
  }
}

extern "C" void kernel_launch(void* const* d_in, const int* in_sizes, int n_in,
                              void* d_out, int out_size, void* d_ws, size_t ws_size,
                              hipStream_t stream) {
  const float* in = (const float*)d_in[0];
  const float* w  = (const float*)d_in[1];
  float* out = (float*)d_out;
  unsigned short* ws_w = (unsigned short*)d_ws;

  if (ws_size >= WS_TOTAL) {
    float* ws_T = (float*)((char*)d_ws + WS_T_OFF);
    short8* ws_x = (short8*)((char*)d_ws + WS_X_OFF);
    float* ws_nb = (float*)((char*)d_ws + WS_NB_OFF);
    prep_kernel<<<dim3(300), 256, 0, stream>>>(in, w, ws_w, ws_T, ws_x);
    nb_kernel<<<dim3(512), 256, 0, stream>>>(ws_T, ws_nb);
    conv_kernel<<<dim3(512), 256, 0, stream>>>(
        ws_w, ws_nb, (const unsigned short*)ws_x, out);
  } else {
    float* ws_T = (float*)((char*)d_ws + WS_W_BYTES);
    prep_kernel_safe<<<dim3(288 + 512), 256, 0, stream>>>(in, w, ws_w, ws_T);
    conv_kernel_safe<<<dim3(64, NN), 256, 0, stream>>>(in, ws_w, ws_T, out);
  }
}